// Round 18
// baseline (252.944 us; speedup 1.0000x reference)
//
#include <hip/hip_runtime.h>
#include <math.h>

typedef unsigned int uint;
typedef unsigned short ushort;
typedef unsigned long long u64;
typedef __attribute__((ext_vector_type(8))) short short8;
typedef __attribute__((ext_vector_type(4))) float f32x4;

// Problem: z (16,256,32,32) fp32, emb (8192,256) fp32. N=16384 rows, K=256, C=8192 codes.
// out (fp32): [0,4194304) z_q (b,c,h,w) | [4194304] loss | [4194305,+16384) idx as float
//
// Pipeline: fused prep (zsum first, zpk, epk) -> bf16-MFMA screen (r4-verified core,
// 2 dispatches) emitting 8-code fine gmax[row][512] + coarse cmax[row][128] ->
// select v5: 16-wave blocks (16 line-sharing rows), coalesced z staging, coarse
// scan -> hit groups -> block-pooled exact fp32 rescore -> per-row u64 atomicMin ->
// u32 idx -> gather (1024 blocks: 64 rows x 64-channel chunk -> 4 blocks/CU of
// latency hiding) + loss.
//
// HW lesson (r9): __launch_bounds__ 2nd arg cap below live set -> scratch spills.
// HW lesson (r10): order-dependent compaction is nondeterministic -> ballot/serial
// prefix + commutative reductions only.
// HW lesson (r12): NT stores bypass L2 write-combining + poison the vmcnt FIFO.
// HW lesson (r13): pipeline register ROTATION out-issued the MFMAs -> full unroll +
// static zf[] indexing (VGPR 100, MfmaUtil 37.5 = 92% of the r14 LDS-pipe cap).
// HW lesson (r16/r17): allocator will NOT hold >~150 VGPR live; r4 gemm structure is
// the verified optimum for this schedule.
// Lesson (r19/r20): select cost = scattered fp32 emb rescore reads (keep 8-code
// fine granularity) + screen scan VALU (fixed by coarse cmax).
// Lesson (r21): rows sharing a 64B z line landed on different XCDs (private L2s) ->
// 4x z over-fetch; fixed by 16-wave blocks + cooperative coalesced staging.
// Lesson (r22): rescore at 16/64 active lanes issued full-wave VALU -> block pool
// packs codes into low thread ids (select 66->48us, VALUBusy 34->19).
// Lesson (r25): zsum-first overlap: 232.8->229.8us.
// Lesson (r27): fusing gather into select's tail REGRESSED (48->85us): two extra
// block-wide barriers serialized a latency-bound phase that the separate kernel
// overlapped across blocks; emb was not L2-hot either (FETCH rose). Reverted;
// instead gather gets 4 blocks/CU via the 64-row x 64-channel-chunk split.
//
// ws: zpk 8MB @0 | epk 4MB | sumz 64KB | gmax 32MB | cmax 4MB | bestI 64KB | loss
#define WS_ZPK  0ull
#define WS_EPK  8388608ull
#define WS_SUMZ 12582912ull
#define WS_GMAX 12648448ull
#define WS_CMAX 46202880ull
#define WS_BEST 50397184ull
#define WS_LOSS 50462720ull

#define DOT_MARGIN 1.5e-4f  // r9 bound: 2*eps_screen + bf16 store ulp ~4.1e-5; >3.5x safety

__device__ __forceinline__ ushort f2bf(float f) {           // RNE fp32->bf16
  uint b = __float_as_uint(f);
  b += 0x7fffu + ((b >> 16) & 1u);
  return (ushort)(b >> 16);
}
__device__ __forceinline__ uint ford(float f) {             // orderable uint
  uint b = __float_as_uint(f);
  return (b & 0x80000000u) ? ~b : (b | 0x80000000u);
}
__device__ __forceinline__ void gload_lds16(const void* g, void* l) {
  __builtin_amdgcn_global_load_lds(
      (const __attribute__((address_space(1))) unsigned int*)g,
      (__attribute__((address_space(3))) unsigned int*)l, 16, 0, 0);
}

// ---------------- fused prep: zsum (blocks 0..63, FIRST — overlaps streaming),
// prep_z/zpk (64..1087), prep_e/epk (1088..2111). Bodies verbatim (r16-verified).
__global__ __launch_bounds__(256) void prep_all(const float* __restrict__ z,
                                                const float* __restrict__ emb,
                                                ushort* __restrict__ zpk,
                                                ushort* __restrict__ epk,
                                                float* __restrict__ sumz) {
  __shared__ float tile[64][65];
  const int bidg = blockIdx.x;
  const int t = threadIdx.x;
  if (bidg < 64) {                                          // ---- zsum (verbatim)
    const int n = (bidg << 8) + t;
    const int b = n >> 10, hw = n & 1023;
    const float* zb = z + b * 262144 + hw;
    float s = 0.f;
#pragma unroll 8
    for (int c = 0; c < 256; ++c) { const float v = zb[c << 10]; s += v * v; }
    sumz[n] = s;
  } else if (bidg < 1088) {                                 // ---- prep_z (zpk only)
    const int bid = bidg - 64;
    const int kt = bid & 3, hwt = (bid >> 2) & 15, b = bid >> 6;
    const int lane = t & 63, grp = t >> 6;
    const float* src = z + b * 262144 + (kt * 64) * 1024 + hwt * 64;
    for (int kk = grp; kk < 64; kk += 4)
      tile[kk][lane] = src[kk * 1024 + lane];               // coalesced over hw
    __syncthreads();
    for (int u = t; u < 512; u += 256) {                    // zpk: 16B frag pieces
      const int n_loc = u & 63, kg = u >> 6;
      const int n = b * 1024 + hwt * 64 + n_loc;
      const int k0 = kt * 64 + kg * 8;
      short8 s;
#pragma unroll
      for (int j = 0; j < 8; ++j) s[j] = (short)f2bf(tile[kg * 8 + j][n_loc]);
      *(short8*)(zpk + (size_t)(n >> 4) * 4096 + (k0 >> 5) * 512 +
                 ((k0 >> 3) & 3) * 128 + (n & 15) * 8) = s;
    }
  } else {                                                  // ---- prep_e
    const int u = (bidg - 1088) * 256 + t;                  // 262144 threads
    const int c = u >> 5, k0 = (u & 31) * 8;
    const float4 v0 = *(const float4*)(emb + c * 256 + k0);
    const float4 v1 = *(const float4*)(emb + c * 256 + k0 + 4);
    short8 s;
    s[0] = (short)f2bf(v0.x); s[1] = (short)f2bf(v0.y);
    s[2] = (short)f2bf(v0.z); s[3] = (short)f2bf(v0.w);
    s[4] = (short)f2bf(v1.x); s[5] = (short)f2bf(v1.y);
    s[6] = (short)f2bf(v1.z); s[7] = (short)f2bf(v1.w);
    *(short8*)(epk + (size_t)(c >> 4) * 4096 + (k0 >> 5) * 512 +
               ((k0 >> 3) & 3) * 128 + (c & 15) * 8) = s;
  }
}

// ---------------- screening GEMM (r4-verified core) — two 1024-block dispatches.
// Epilogue: fine gmax[row][512] (cix = x*64+yy*4+q; 64B line = one XCD; WRITE exact)
// + cmax[row][128] bf16 panel max at col x*16+yy. RNE-monotone fmax => cmax equals
// the max of the stored fine words -> select thresholds bit-identical to v1.
__global__ __launch_bounds__(256) void gemm_screen(const ushort* __restrict__ zpk,
                                                   const ushort* __restrict__ epk,
                                                   uint* __restrict__ gmax,
                                                   ushort* __restrict__ cmax,
                                                   int boff) {
  __shared__ ushort Cs[16384];   // 32 KB: 32 frags x 1KB, frag f = c16loc*8 + k32
  const int t = threadIdx.x;
  const int w = t >> 6, lane = t & 63;
  const int bid = blockIdx.x + boff;
  const int x = bid & 7, y = bid >> 3;
  const int yyv = y & 15;
  const int colb = yyv * 8 + x;            // 0..127; XCD x owns 16 panels (512KB, L2)
  const int rowg = y >> 4;                 // 0..15
  const int n0 = rowg << 10;
  const int m16 = lane & 15, q = lane >> 4;
  const int cix = x * 64 + yyv * 4 + q;    // gmax col: 64B line = one XCD (r13)

  // stage code panel once: 8 coalesced 1KB DMAs per wave
#pragma unroll
  for (int f2 = 0; f2 < 8; ++f2) {
    const int f = w * 8 + f2;
    gload_lds16(epk + (size_t)colb * 16384 + f * 512 + lane * 8, (char*)Cs + f * 1024);
  }

  // z fragment address for flattened step v (0..31), row-frag jr (0..3):
  //   zw + ((v>>3)*16 + jr)*4096 + (v&7)*512   (elements)
  const ushort* zw = zpk + ((size_t)(n0 >> 4) + w * 4) * 4096 + lane * 8;

  // fully static pipeline: zf[v] loaded at step v-3, consumed at step v.
  short8 zf[32][4];
#pragma unroll
  for (int v = 0; v < 3; ++v)              // prologue primes 3 steps (overlaps DMA)
#pragma unroll
    for (int jr = 0; jr < 4; ++jr)
      zf[v][jr] = *(const short8*)(zw + ((size_t)((v >> 3) * 16 + jr)) * 4096 +
                                   (v & 7) * 512);
  __syncthreads();                         // only barrier in the kernel

#pragma unroll
  for (int strip = 0; strip < 4; ++strip) {
    const int rbase = n0 + strip * 256 + w * 64;
    f32x4 acc[4][4];                       // [ic][jr]
#pragma unroll
    for (int i = 0; i < 4; ++i)
#pragma unroll
      for (int j = 0; j < 4; ++j) acc[i][j] = {0.f, 0.f, 0.f, 0.f};

#pragma unroll
    for (int s32 = 0; s32 < 8; ++s32) {    // k32 steps over K=256 (all static)
      const int v = strip * 8 + s32;
      if (v + 3 < 32) {                    // static condition: prefetch step v+3
        const int u = v + 3;
#pragma unroll
        for (int jr = 0; jr < 4; ++jr)
          zf[u][jr] = *(const short8*)(zw + ((size_t)((u >> 3) * 16 + jr)) * 4096 +
                                       (u & 7) * 512);
      }
      short8 cv[4];
#pragma unroll
      for (int ic = 0; ic < 4; ++ic)
        cv[ic] = *(const short8*)&Cs[(size_t)(ic * 8 + s32) * 512 + lane * 8];
#pragma unroll
      for (int ic = 0; ic < 4; ++ic)
#pragma unroll
        for (int jr = 0; jr < 4; ++jr)
          acc[ic][jr] = __builtin_amdgcn_mfma_f32_16x16x32_bf16(cv[ic], zf[v][jr],
                                                                acc[ic][jr], 0, 0, 0);
    }

    // epilogue: D row=code(q*4+reg), col=z-row(m16). 8-group g0 = q{0,1} regs,
    // g1 = q{2,3}. in-lane reg-max -> xor16 -> xor32 -> pack; pm = panel max.
#pragma unroll
    for (int jr = 0; jr < 4; ++jr) {
      uint pk[4];
      float pm = -INFINITY;
#pragma unroll
      for (int ic = 0; ic < 4; ++ic) {
        float m = fmaxf(fmaxf(acc[ic][jr][0], acc[ic][jr][1]),
                        fmaxf(acc[ic][jr][2], acc[ic][jr][3]));
        m = fmaxf(m, __shfl_xor(m, 16, 64));     // 8-group max (own half)
        const float o = __shfl_xor(m, 32, 64);   // other half's 8-group max
        pm = fmaxf(pm, fmaxf(m, o));
        const float glo = (q & 2) ? o : m;
        const float ghi = (q & 2) ? m : o;
        pk[ic] = (uint)f2bf(glo) | ((uint)f2bf(ghi) << 16);
      }
      const uint sv = (q == 0) ? pk[0] : (q == 1) ? pk[1] : (q == 2) ? pk[2] : pk[3];
      const int row = rbase + jr * 16 + m16;
      gmax[(size_t)row * 512 + cix] = sv;        // plain store -> L2 combining (r13)
      if (q == 0) cmax[(size_t)row * 128 + x * 16 + yyv] = f2bf(pm);
    }
  }
}

// ---------------- select v5: 1024 threads = 16 waves = 16 line-sharing rows.
// Coalesced z staging (r21) -> per-wave coarse scan + hit-group list (deterministic
// serial order, cap 64) -> block prefix -> pooled rescore: thread id -> (pool
// entry id>>3, code id&7); exact fp32 sequential-k chain per code (byte-identical
// to validated); per-row LDS u64 atomicMin (commutative -> deterministic).
__global__ __launch_bounds__(1024) void select_rescore(const uint* __restrict__ gmax,
                                                       const ushort* __restrict__ cmax,
                                                       const float* __restrict__ z,
                                                       const float* __restrict__ emb,
                                                       const float* __restrict__ sumz,
                                                       uint* __restrict__ bestI) {
  const int t = threadIdx.x, w = t >> 6, lane = t & 63;
  const int n0 = blockIdx.x << 4;          // 16 rows per block, same b
  const int n = n0 + w;                    // this wave's row
  __shared__ float zrow[16][260];          // pad: 8-way write aliasing ~0.4us (m136)
  __shared__ ushort hits[16][64];
  __shared__ int nhs[16];
  __shared__ float szs[16];
  __shared__ u64 rmin[16];
  __shared__ uint pool[1024];              // (row<<13)|groupbase; 16*64 max = 1024
  const int b_i = n0 >> 10, hw0 = n0 & 1023;
  const float* zb = z + b_i * 262144 + hw0;
#pragma unroll
  for (int i = 0; i < 4; ++i) {            // 4096 floats, r fastest: 64B-coalesced
    const int u = t + i * 1024;
    const int c = u >> 4, r = u & 15;
    zrow[r][c] = zb[c * 1024 + r];
  }
  if (t < 16) { szs[t] = sumz[n0 + t]; rmin[t] = ~0ull; }

  // coarse scan: 128 panel maxes = 64 uints, one per lane
  const uint cu = ((const uint*)cmax)[(size_t)n * 64 + lane];
  const float c0 = __uint_as_float(cu << 16);            // panel 2*lane
  const float c1 = __uint_as_float(cu & 0xffff0000u);    // panel 2*lane+1
  float m = fmaxf(c0, c1);
#pragma unroll
  for (int off = 1; off < 64; off <<= 1) m = fmaxf(m, __shfl_xor(m, off, 64));
  const float thr = m - DOT_MARGIN;

  u64 m0 = __ballot(c0 >= thr);
  u64 m1 = __ballot(c1 >= thr);
  int nh = 0;                              // wave-uniform serial order (determ.)
  while (m0 | m1) {
    int p;
    if (m0) { const int s = (int)__builtin_ctzll(m0); m0 &= m0 - 1; p = s * 2; }
    else    { const int s = (int)__builtin_ctzll(m1); m1 &= m1 - 1; p = s * 2 + 1; }
    const int xx = p >> 4, yy = p & 15;    // cmax col p = x*16+yy
    const int cb = (yy * 8 + xx) * 64;     // panel's first code
    const uint4 fw = *(const uint4*)(gmax + (size_t)n * 512 + xx * 64 + yy * 4);
    const uint fq[4] = {fw.x, fw.y, fw.z, fw.w};
#pragma unroll
    for (int qq = 0; qq < 4; ++qq) {       // word qq: lo = codes cb+qq*16+0..7
      if (__uint_as_float(fq[qq] << 16) >= thr && nh < 64)
        hits[w][nh++] = (ushort)(cb + qq * 16);
      if (__uint_as_float(fq[qq] & 0xffff0000u) >= thr && nh < 64)
        hits[w][nh++] = (ushort)(cb + qq * 16 + 8);
    }
  }
  if (lane == 0) nhs[w] = nh;
  __syncthreads();

  // deterministic block prefix; copy hit lists into the packed pool
  int off = 0, total = 0;
#pragma unroll
  for (int ww = 0; ww < 16; ++ww) {
    const int v = nhs[ww];
    off += (ww < w) ? v : 0;
    total += v;
  }
  if (lane < nh) pool[off + lane] = ((uint)w << 13) | (uint)hits[w][lane];
  __syncthreads();

  // pooled rescore: codes packed into low thread ids -> ~4x fewer VALU wave-instrs
  const int T = total * 8;
  for (int id = t; id < T; id += 1024) {
    const uint e = pool[id >> 3];
    const int r = (int)(e >> 13);
    const int c = (int)(e & 8191u) + (id & 7);
    const float4* ea = (const float4*)(emb + c * 256);
    const float4* za = (const float4*)&zrow[r][0];
    float sdot = 0.f, se = 0.f;
#pragma unroll 8
    for (int k = 0; k < 64; ++k) {          // validated sequential-k fp32 numerics
      const float4 a = za[k], e4 = ea[k];
      sdot = fmaf(a.x, e4.x, sdot); sdot = fmaf(a.y, e4.y, sdot);
      sdot = fmaf(a.z, e4.z, sdot); sdot = fmaf(a.w, e4.w, sdot);
      se = fmaf(e4.x, e4.x, se); se = fmaf(e4.y, e4.y, se);
      se = fmaf(e4.z, e4.z, se); se = fmaf(e4.w, e4.w, se);
    }
    const float d = (szs[r] + se) - 2.f * sdot;  // matches ref: (sumz+sume)-2*dot
    const u64 key = ((u64)ford(d) << 32) | (uint)c;
    atomicMin(&rmin[r], key);              // commutative min: order-independent
  }
  __syncthreads();
  if (t < 16) bestI[n0 + t] = (uint)(rmin[t] & 0xffffffffu);   // idx only
}

// ---------------- gather z_q, idx, loss + fused finalize (done-counter)
// 1024 blocks (r27): 64 rows x 64-channel chunk -> 4 blocks/CU of latency hiding
// for the scattered emb reads (the 256-block config was 1 block/CU, 4 waves).
__global__ __launch_bounds__(256) void gather_kernel(const float* __restrict__ z,
                                                     const float* __restrict__ emb,
                                                     const uint* __restrict__ bestI,
                                                     float* __restrict__ out,
                                                     double* __restrict__ loss_acc,
                                                     uint* __restrict__ done) {
  const int t = threadIdx.x;
  const int bid = blockIdx.x;              // 0..1023
  const int n = ((bid >> 2) << 6) + (t & 63);
  const int cc = bid & 3;                  // channel chunk: [cc*64, cc*64+64)
  const int idx = (int)bestI[n];
  const int b_i = n >> 10, hw = n & 1023;
  const int c0 = cc * 64 + (t >> 6);
  const float* zb = z + b_i * 262144 + hw;
  float* ob = out + b_i * 262144 + hw;
  const float* eb = emb + idx * 256;
  float lsum = 0.f;
#pragma unroll 4
  for (int c = c0; c < cc * 64 + 64; c += 4) {
    const float ev = eb[c];
    const float zv = zb[c << 10];
    ob[c << 10] = ev;
    const float d = ev - zv;
    lsum += d * d;
  }
  if (cc == 0 && (t >> 6) == 0) out[4194305 + n] = (float)idx;
#pragma unroll
  for (int off = 32; off; off >>= 1) lsum += __shfl_down(lsum, off, 64);
  __shared__ double wsum[4];
  if ((t & 63) == 0) wsum[t >> 6] = (double)lsum;
  __syncthreads();
  if (t == 0) {
    atomicAdd(loss_acc, wsum[0] + wsum[1] + wsum[2] + wsum[3]);
    __threadfence();
    if (atomicAdd(done, 1u) == 1023u) {      // last of 1024 blocks
      __threadfence();
      out[4194304] = (float)(1.25 * (*(volatile double*)loss_acc) / 4194304.0);
    }
  }
}

// ---------------- launch
extern "C" void kernel_launch(void* const* d_in, const int* in_sizes, int n_in,
                              void* d_out, int out_size, void* d_ws, size_t ws_size,
                              hipStream_t stream) {
  const float* z = (const float*)d_in[0];
  const float* emb = (const float*)d_in[1];
  float* out = (float*)d_out;
  char* ws = (char*)d_ws;
  ushort* zpk = (ushort*)(ws + WS_ZPK);
  ushort* epk = (ushort*)(ws + WS_EPK);
  float* sumz = (float*)(ws + WS_SUMZ);
  uint* gmax = (uint*)(ws + WS_GMAX);
  ushort* cmax = (ushort*)(ws + WS_CMAX);
  uint* bestI = (uint*)(ws + WS_BEST);
  double* loss_acc = (double*)(ws + WS_LOSS);
  uint* done = (uint*)(ws + WS_LOSS + 8);

  hipMemsetAsync(ws + WS_LOSS, 0, 16, stream);   // loss_acc + done ctr
  prep_all<<<2112, 256, 0, stream>>>(z, emb, zpk, epk, sumz);
  gemm_screen<<<1024, 256, 0, stream>>>(zpk, epk, gmax, cmax, 0);     // rowg 0..7
  gemm_screen<<<1024, 256, 0, stream>>>(zpk, epk, gmax, cmax, 1024);  // rowg 8..15
  select_rescore<<<1024, 1024, 0, stream>>>(gmax, cmax, z, emb, sumz, bestI);
  gather_kernel<<<1024, 256, 0, stream>>>(z, emb, bestI, out, loss_acc, done);
}

// Round 19
// 226.697 us; speedup vs baseline: 1.1158x; 1.1158x over previous
//
#include <hip/hip_runtime.h>
#include <math.h>

typedef unsigned int uint;
typedef unsigned short ushort;
typedef unsigned long long u64;
typedef __attribute__((ext_vector_type(8))) short short8;
typedef __attribute__((ext_vector_type(4))) float f32x4;

// Problem: z (16,256,32,32) fp32, emb (8192,256) fp32. N=16384 rows, K=256, C=8192 codes.
// out (fp32): [0,4194304) z_q (b,c,h,w) | [4194304] loss | [4194305,+16384) idx as float
//
// Pipeline (4 graph nodes): fused prep (zsum first, zpk, epk, + zeroes loss/done) ->
// bf16-MFMA screen (r4-verified core, ONE 2048-block dispatch) emitting 8-code fine
// gmax[row][512] + coarse cmax[row][128] -> select v5 (16-wave blocks, coalesced z
// staging, coarse scan -> hit groups -> block-pooled exact fp32 rescore -> per-row
// u64 atomicMin -> u32 idx) -> gather (256 blocks) + loss.
//
// HW lesson (r9): __launch_bounds__ 2nd arg cap below live set -> scratch spills.
// HW lesson (r10): order-dependent compaction is nondeterministic -> ballot/serial
// prefix + commutative reductions only.
// HW lesson (r12): NT stores bypass L2 write-combining + poison the vmcnt FIFO.
// HW lesson (r13): pipeline register ROTATION out-issued the MFMAs -> full unroll +
// static zf[] indexing (VGPR 100, MfmaUtil 37.5 = 92% of the r14 LDS-pipe cap).
// HW lesson (r16/r17): allocator will NOT hold >~150 VGPR live; r4 gemm structure is
// the verified optimum for this schedule.
// Lesson (r19/r20): select cost = scattered fp32 emb rescore reads (keep 8-code
// fine granularity) + screen scan VALU (fixed by coarse cmax).
// Lesson (r21): rows sharing a 64B z line landed on different XCDs (private L2s) ->
// 4x z over-fetch; fixed by 16-wave blocks + cooperative coalesced staging.
// Lesson (r22): rescore at 16/64 active lanes issued full-wave VALU -> block pool
// packs codes into low thread ids (select 66->48us, VALUBusy 34->19).
// Lesson (r25): zsum-first overlap: 232.8->229.8us.
// Lesson (r27): fusing gather into select serialized a latency-bound phase behind
// block barriers -> +15us total. Keep gather separate.
// Lesson (r28): gather at 1024 blocks regressed total (229.8->252.9, controls held);
// 256-block gather is the verified config. Dispatch-level deltas don't compose ->
// attack the INTER-dispatch structure: ~70us of the total is not in any measured
// kernel. This round: 6 graph nodes -> 4 (merge gemm halves; fold memset into prep).
//
// ws: zpk 8MB @0 | epk 4MB | sumz 64KB | gmax 32MB | cmax 4MB | bestI 64KB | loss
#define WS_ZPK  0ull
#define WS_EPK  8388608ull
#define WS_SUMZ 12582912ull
#define WS_GMAX 12648448ull
#define WS_CMAX 46202880ull
#define WS_BEST 50397184ull
#define WS_LOSS 50462720ull

#define DOT_MARGIN 1.5e-4f  // r9 bound: 2*eps_screen + bf16 store ulp ~4.1e-5; >3.5x safety

__device__ __forceinline__ ushort f2bf(float f) {           // RNE fp32->bf16
  uint b = __float_as_uint(f);
  b += 0x7fffu + ((b >> 16) & 1u);
  return (ushort)(b >> 16);
}
__device__ __forceinline__ uint ford(float f) {             // orderable uint
  uint b = __float_as_uint(f);
  return (b & 0x80000000u) ? ~b : (b | 0x80000000u);
}
__device__ __forceinline__ void gload_lds16(const void* g, void* l) {
  __builtin_amdgcn_global_load_lds(
      (const __attribute__((address_space(1))) unsigned int*)g,
      (__attribute__((address_space(3))) unsigned int*)l, 16, 0, 0);
}

// ---------------- fused prep: zsum (blocks 0..63, FIRST — overlaps streaming),
// prep_z/zpk (64..1087), prep_e/epk (1088..2111). Bodies verbatim (r16-verified).
// Block 0 / t 0 additionally zeroes loss_acc+done (replaces the memset node; prep
// strictly precedes all readers).
__global__ __launch_bounds__(256) void prep_all(const float* __restrict__ z,
                                                const float* __restrict__ emb,
                                                ushort* __restrict__ zpk,
                                                ushort* __restrict__ epk,
                                                float* __restrict__ sumz,
                                                double* __restrict__ loss_acc,
                                                uint* __restrict__ done) {
  __shared__ float tile[64][65];
  const int bidg = blockIdx.x;
  const int t = threadIdx.x;
  if (bidg < 64) {                                          // ---- zsum (verbatim)
    if (bidg == 0 && t == 0) { *loss_acc = 0.0; *done = 0u; }
    const int n = (bidg << 8) + t;
    const int b = n >> 10, hw = n & 1023;
    const float* zb = z + b * 262144 + hw;
    float s = 0.f;
#pragma unroll 8
    for (int c = 0; c < 256; ++c) { const float v = zb[c << 10]; s += v * v; }
    sumz[n] = s;
  } else if (bidg < 1088) {                                 // ---- prep_z (zpk only)
    const int bid = bidg - 64;
    const int kt = bid & 3, hwt = (bid >> 2) & 15, b = bid >> 6;
    const int lane = t & 63, grp = t >> 6;
    const float* src = z + b * 262144 + (kt * 64) * 1024 + hwt * 64;
    for (int kk = grp; kk < 64; kk += 4)
      tile[kk][lane] = src[kk * 1024 + lane];               // coalesced over hw
    __syncthreads();
    for (int u = t; u < 512; u += 256) {                    // zpk: 16B frag pieces
      const int n_loc = u & 63, kg = u >> 6;
      const int n = b * 1024 + hwt * 64 + n_loc;
      const int k0 = kt * 64 + kg * 8;
      short8 s;
#pragma unroll
      for (int j = 0; j < 8; ++j) s[j] = (short)f2bf(tile[kg * 8 + j][n_loc]);
      *(short8*)(zpk + (size_t)(n >> 4) * 4096 + (k0 >> 5) * 512 +
                 ((k0 >> 3) & 3) * 128 + (n & 15) * 8) = s;
    }
  } else {                                                  // ---- prep_e
    const int u = (bidg - 1088) * 256 + t;                  // 262144 threads
    const int c = u >> 5, k0 = (u & 31) * 8;
    const float4 v0 = *(const float4*)(emb + c * 256 + k0);
    const float4 v1 = *(const float4*)(emb + c * 256 + k0 + 4);
    short8 s;
    s[0] = (short)f2bf(v0.x); s[1] = (short)f2bf(v0.y);
    s[2] = (short)f2bf(v0.z); s[3] = (short)f2bf(v0.w);
    s[4] = (short)f2bf(v1.x); s[5] = (short)f2bf(v1.y);
    s[6] = (short)f2bf(v1.z); s[7] = (short)f2bf(v1.w);
    *(short8*)(epk + (size_t)(c >> 4) * 4096 + (k0 >> 5) * 512 +
               ((k0 >> 3) & 3) * 128 + (c & 15) * 8) = s;
  }
}

// ---------------- screening GEMM (r4-verified core) — ONE 2048-block dispatch
// (r9's 2-way split was profiler-visibility only; merged back to drop a graph node).
// Epilogue: fine gmax[row][512] (cix = x*64+yy*4+q; 64B line = one XCD; WRITE exact)
// + cmax[row][128] bf16 panel max at col x*16+yy. RNE-monotone fmax => cmax equals
// the max of the stored fine words -> select thresholds bit-identical to v1.
__global__ __launch_bounds__(256) void gemm_screen(const ushort* __restrict__ zpk,
                                                   const ushort* __restrict__ epk,
                                                   uint* __restrict__ gmax,
                                                   ushort* __restrict__ cmax) {
  __shared__ ushort Cs[16384];   // 32 KB: 32 frags x 1KB, frag f = c16loc*8 + k32
  const int t = threadIdx.x;
  const int w = t >> 6, lane = t & 63;
  const int bid = blockIdx.x;              // 0..2047
  const int x = bid & 7, y = bid >> 3;
  const int yyv = y & 15;
  const int colb = yyv * 8 + x;            // 0..127; XCD x owns 16 panels (512KB, L2)
  const int rowg = y >> 4;                 // 0..15
  const int n0 = rowg << 10;
  const int m16 = lane & 15, q = lane >> 4;
  const int cix = x * 64 + yyv * 4 + q;    // gmax col: 64B line = one XCD (r13)

  // stage code panel once: 8 coalesced 1KB DMAs per wave
#pragma unroll
  for (int f2 = 0; f2 < 8; ++f2) {
    const int f = w * 8 + f2;
    gload_lds16(epk + (size_t)colb * 16384 + f * 512 + lane * 8, (char*)Cs + f * 1024);
  }

  // z fragment address for flattened step v (0..31), row-frag jr (0..3):
  //   zw + ((v>>3)*16 + jr)*4096 + (v&7)*512   (elements)
  const ushort* zw = zpk + ((size_t)(n0 >> 4) + w * 4) * 4096 + lane * 8;

  // fully static pipeline: zf[v] loaded at step v-3, consumed at step v.
  short8 zf[32][4];
#pragma unroll
  for (int v = 0; v < 3; ++v)              // prologue primes 3 steps (overlaps DMA)
#pragma unroll
    for (int jr = 0; jr < 4; ++jr)
      zf[v][jr] = *(const short8*)(zw + ((size_t)((v >> 3) * 16 + jr)) * 4096 +
                                   (v & 7) * 512);
  __syncthreads();                         // only barrier in the kernel

#pragma unroll
  for (int strip = 0; strip < 4; ++strip) {
    const int rbase = n0 + strip * 256 + w * 64;
    f32x4 acc[4][4];                       // [ic][jr]
#pragma unroll
    for (int i = 0; i < 4; ++i)
#pragma unroll
      for (int j = 0; j < 4; ++j) acc[i][j] = {0.f, 0.f, 0.f, 0.f};

#pragma unroll
    for (int s32 = 0; s32 < 8; ++s32) {    // k32 steps over K=256 (all static)
      const int v = strip * 8 + s32;
      if (v + 3 < 32) {                    // static condition: prefetch step v+3
        const int u = v + 3;
#pragma unroll
        for (int jr = 0; jr < 4; ++jr)
          zf[u][jr] = *(const short8*)(zw + ((size_t)((u >> 3) * 16 + jr)) * 4096 +
                                       (u & 7) * 512);
      }
      short8 cv[4];
#pragma unroll
      for (int ic = 0; ic < 4; ++ic)
        cv[ic] = *(const short8*)&Cs[(size_t)(ic * 8 + s32) * 512 + lane * 8];
#pragma unroll
      for (int ic = 0; ic < 4; ++ic)
#pragma unroll
        for (int jr = 0; jr < 4; ++jr)
          acc[ic][jr] = __builtin_amdgcn_mfma_f32_16x16x32_bf16(cv[ic], zf[v][jr],
                                                                acc[ic][jr], 0, 0, 0);
    }

    // epilogue: D row=code(q*4+reg), col=z-row(m16). 8-group g0 = q{0,1} regs,
    // g1 = q{2,3}. in-lane reg-max -> xor16 -> xor32 -> pack; pm = panel max.
#pragma unroll
    for (int jr = 0; jr < 4; ++jr) {
      uint pk[4];
      float pm = -INFINITY;
#pragma unroll
      for (int ic = 0; ic < 4; ++ic) {
        float m = fmaxf(fmaxf(acc[ic][jr][0], acc[ic][jr][1]),
                        fmaxf(acc[ic][jr][2], acc[ic][jr][3]));
        m = fmaxf(m, __shfl_xor(m, 16, 64));     // 8-group max (own half)
        const float o = __shfl_xor(m, 32, 64);   // other half's 8-group max
        pm = fmaxf(pm, fmaxf(m, o));
        const float glo = (q & 2) ? o : m;
        const float ghi = (q & 2) ? m : o;
        pk[ic] = (uint)f2bf(glo) | ((uint)f2bf(ghi) << 16);
      }
      const uint sv = (q == 0) ? pk[0] : (q == 1) ? pk[1] : (q == 2) ? pk[2] : pk[3];
      const int row = rbase + jr * 16 + m16;
      gmax[(size_t)row * 512 + cix] = sv;        // plain store -> L2 combining (r13)
      if (q == 0) cmax[(size_t)row * 128 + x * 16 + yyv] = f2bf(pm);
    }
  }
}

// ---------------- select v5: 1024 threads = 16 waves = 16 line-sharing rows.
// Coalesced z staging (r21) -> per-wave coarse scan + hit-group list (deterministic
// serial order, cap 64) -> block prefix -> pooled rescore: thread id -> (pool
// entry id>>3, code id&7); exact fp32 sequential-k chain per code (byte-identical
// to validated); per-row LDS u64 atomicMin (commutative -> deterministic).
__global__ __launch_bounds__(1024) void select_rescore(const uint* __restrict__ gmax,
                                                       const ushort* __restrict__ cmax,
                                                       const float* __restrict__ z,
                                                       const float* __restrict__ emb,
                                                       const float* __restrict__ sumz,
                                                       uint* __restrict__ bestI) {
  const int t = threadIdx.x, w = t >> 6, lane = t & 63;
  const int n0 = blockIdx.x << 4;          // 16 rows per block, same b
  const int n = n0 + w;                    // this wave's row
  __shared__ float zrow[16][260];          // pad: 8-way write aliasing ~0.4us (m136)
  __shared__ ushort hits[16][64];
  __shared__ int nhs[16];
  __shared__ float szs[16];
  __shared__ u64 rmin[16];
  __shared__ uint pool[1024];              // (row<<13)|groupbase; 16*64 max = 1024
  const int b_i = n0 >> 10, hw0 = n0 & 1023;
  const float* zb = z + b_i * 262144 + hw0;
#pragma unroll
  for (int i = 0; i < 4; ++i) {            // 4096 floats, r fastest: 64B-coalesced
    const int u = t + i * 1024;
    const int c = u >> 4, r = u & 15;
    zrow[r][c] = zb[c * 1024 + r];
  }
  if (t < 16) { szs[t] = sumz[n0 + t]; rmin[t] = ~0ull; }

  // coarse scan: 128 panel maxes = 64 uints, one per lane
  const uint cu = ((const uint*)cmax)[(size_t)n * 64 + lane];
  const float c0 = __uint_as_float(cu << 16);            // panel 2*lane
  const float c1 = __uint_as_float(cu & 0xffff0000u);    // panel 2*lane+1
  float m = fmaxf(c0, c1);
#pragma unroll
  for (int off = 1; off < 64; off <<= 1) m = fmaxf(m, __shfl_xor(m, off, 64));
  const float thr = m - DOT_MARGIN;

  u64 m0 = __ballot(c0 >= thr);
  u64 m1 = __ballot(c1 >= thr);
  int nh = 0;                              // wave-uniform serial order (determ.)
  while (m0 | m1) {
    int p;
    if (m0) { const int s = (int)__builtin_ctzll(m0); m0 &= m0 - 1; p = s * 2; }
    else    { const int s = (int)__builtin_ctzll(m1); m1 &= m1 - 1; p = s * 2 + 1; }
    const int xx = p >> 4, yy = p & 15;    // cmax col p = x*16+yy
    const int cb = (yy * 8 + xx) * 64;     // panel's first code
    const uint4 fw = *(const uint4*)(gmax + (size_t)n * 512 + xx * 64 + yy * 4);
    const uint fq[4] = {fw.x, fw.y, fw.z, fw.w};
#pragma unroll
    for (int qq = 0; qq < 4; ++qq) {       // word qq: lo = codes cb+qq*16+0..7
      if (__uint_as_float(fq[qq] << 16) >= thr && nh < 64)
        hits[w][nh++] = (ushort)(cb + qq * 16);
      if (__uint_as_float(fq[qq] & 0xffff0000u) >= thr && nh < 64)
        hits[w][nh++] = (ushort)(cb + qq * 16 + 8);
    }
  }
  if (lane == 0) nhs[w] = nh;
  __syncthreads();

  // deterministic block prefix; copy hit lists into the packed pool
  int off = 0, total = 0;
#pragma unroll
  for (int ww = 0; ww < 16; ++ww) {
    const int v = nhs[ww];
    off += (ww < w) ? v : 0;
    total += v;
  }
  if (lane < nh) pool[off + lane] = ((uint)w << 13) | (uint)hits[w][lane];
  __syncthreads();

  // pooled rescore: codes packed into low thread ids -> ~4x fewer VALU wave-instrs
  const int T = total * 8;
  for (int id = t; id < T; id += 1024) {
    const uint e = pool[id >> 3];
    const int r = (int)(e >> 13);
    const int c = (int)(e & 8191u) + (id & 7);
    const float4* ea = (const float4*)(emb + c * 256);
    const float4* za = (const float4*)&zrow[r][0];
    float sdot = 0.f, se = 0.f;
#pragma unroll 8
    for (int k = 0; k < 64; ++k) {          // validated sequential-k fp32 numerics
      const float4 a = za[k], e4 = ea[k];
      sdot = fmaf(a.x, e4.x, sdot); sdot = fmaf(a.y, e4.y, sdot);
      sdot = fmaf(a.z, e4.z, sdot); sdot = fmaf(a.w, e4.w, sdot);
      se = fmaf(e4.x, e4.x, se); se = fmaf(e4.y, e4.y, se);
      se = fmaf(e4.z, e4.z, se); se = fmaf(e4.w, e4.w, se);
    }
    const float d = (szs[r] + se) - 2.f * sdot;  // matches ref: (sumz+sume)-2*dot
    const u64 key = ((u64)ford(d) << 32) | (uint)c;
    atomicMin(&rmin[r], key);              // commutative min: order-independent
  }
  __syncthreads();
  if (t < 16) bestI[n0 + t] = (uint)(rmin[t] & 0xffffffffu);   // idx only
}

// ---------------- gather z_q, idx, loss + fused finalize (done-counter)
// (r16/r28-verified config: 256 blocks, 64 rows x full 256-channel sweep each)
__global__ __launch_bounds__(256) void gather_kernel(const float* __restrict__ z,
                                                     const float* __restrict__ emb,
                                                     const uint* __restrict__ bestI,
                                                     float* __restrict__ out,
                                                     double* __restrict__ loss_acc,
                                                     uint* __restrict__ done) {
  const int t = threadIdx.x;
  const int n0 = blockIdx.x << 6;
  const int n = n0 + (t & 63);
  const int idx = (int)bestI[n];
  const int b_i = n >> 10, hw = n & 1023;
  const int c0 = t >> 6;
  const float* zb = z + b_i * 262144 + hw;
  float* ob = out + b_i * 262144 + hw;
  const float* eb = emb + idx * 256;
  float lsum = 0.f;
#pragma unroll 4
  for (int c = c0; c < 256; c += 4) {
    const float ev = eb[c];
    const float zv = zb[c << 10];
    ob[c << 10] = ev;
    const float d = ev - zv;
    lsum += d * d;
  }
  if (c0 == 0) out[4194305 + n] = (float)idx;
#pragma unroll
  for (int off = 32; off; off >>= 1) lsum += __shfl_down(lsum, off, 64);
  __shared__ double wsum[4];
  if ((t & 63) == 0) wsum[t >> 6] = (double)lsum;
  __syncthreads();
  if (t == 0) {
    atomicAdd(loss_acc, wsum[0] + wsum[1] + wsum[2] + wsum[3]);
    __threadfence();
    if (atomicAdd(done, 1u) == 255u) {       // last of 256 blocks
      __threadfence();
      out[4194304] = (float)(1.25 * (*(volatile double*)loss_acc) / 4194304.0);
    }
  }
}

// ---------------- launch (4 graph nodes)
extern "C" void kernel_launch(void* const* d_in, const int* in_sizes, int n_in,
                              void* d_out, int out_size, void* d_ws, size_t ws_size,
                              hipStream_t stream) {
  const float* z = (const float*)d_in[0];
  const float* emb = (const float*)d_in[1];
  float* out = (float*)d_out;
  char* ws = (char*)d_ws;
  ushort* zpk = (ushort*)(ws + WS_ZPK);
  ushort* epk = (ushort*)(ws + WS_EPK);
  float* sumz = (float*)(ws + WS_SUMZ);
  uint* gmax = (uint*)(ws + WS_GMAX);
  ushort* cmax = (ushort*)(ws + WS_CMAX);
  uint* bestI = (uint*)(ws + WS_BEST);
  double* loss_acc = (double*)(ws + WS_LOSS);
  uint* done = (uint*)(ws + WS_LOSS + 8);

  prep_all<<<2112, 256, 0, stream>>>(z, emb, zpk, epk, sumz, loss_acc, done);
  gemm_screen<<<2048, 256, 0, stream>>>(zpk, epk, gmax, cmax);
  select_rescore<<<1024, 1024, 0, stream>>>(gmax, cmax, z, emb, sumz, bestI);
  gather_kernel<<<256, 256, 0, stream>>>(z, emb, bestI, out, loss_acc, done);
}